// Round 12
// baseline (335.621 us; speedup 1.0000x reference)
//
#include <hip/hip_runtime.h>
#include <hip/hip_bf16.h>
#include <stdint.h>

#define BB 4
#define NN 4096
#define DD 1024
#define EE 8
#define MM 512
#define BN (BB*NN)   // 16384

#define FRONT_GATE 512
#define FRONT_CONV 2048
#define SKBLK 4      // sinkhorn blocks (1 per batch, 512 threads, LDS-local)

typedef __bf16 bf16x8 __attribute__((ext_vector_type(8)));
typedef float  floatx4 __attribute__((ext_vector_type(4)));

typedef const __attribute__((address_space(1))) void* gptr_t;
typedef __attribute__((address_space(3))) void* lptr_t;

__device__ __forceinline__ unsigned short f2bf(float f) {
    union { float f; unsigned u; } v; v.f = f;
    unsigned r = v.u + 0x7fffu + ((v.u >> 16) & 1u);   // round-to-nearest-even
    return (unsigned short)(r >> 16);
}

// raw HW transcendentals: v_exp_f32 = 2^x, v_log_f32 = log2(x), 1 instr each.
// (round-9 fix: precise expf/logf lower to ~10-op OCML sequences; the sinkhorn
// tail on 4 CUs was libm-expansion-bound at ~60 us)
__device__ __forceinline__ float fexp2(float x) { return __builtin_amdgcn_exp2f(x); }
__device__ __forceinline__ float flog2(float x) { return __builtin_amdgcn_logf(x); }

// packed tree reduction: acc[8] per lane summed over 64 lanes.
// returns: lane l (any l) holds full sum of expert bitrev3(l&7) = ((l&1)<<2)|(l&2)|((l&4)>>2)
__device__ __forceinline__ float gate_reduce8(const float acc[8], int lane) {
    float k1[4];
#pragma unroll
    for (int e = 0; e < 4; e++) {
        float a = acc[e]     + __shfl_xor(acc[e],     1, 64);
        float b = acc[e + 4] + __shfl_xor(acc[e + 4], 1, 64);
        k1[e] = (lane & 1) ? b : a;
    }
    float k2[2];
#pragma unroll
    for (int e = 0; e < 2; e++) {
        float a = k1[e]     + __shfl_xor(k1[e],     2, 64);
        float b = k1[e + 2] + __shfl_xor(k1[e + 2], 2, 64);
        k2[e] = (lane & 2) ? b : a;
    }
    float a = k2[0] + __shfl_xor(k2[0], 4, 64);
    float b = k2[1] + __shfl_xor(k2[1], 4, 64);
    float v = (lane & 4) ? b : a;
    v += __shfl_xor(v, 8, 64);
    v += __shfl_xor(v, 16, 64);
    v += __shfl_xor(v, 32, 64);
    return v;
}

// block-level column reduction: part[8] per thread -> c[8] (log2 of column sums).
// Uses red/bcm LDS; 2 barriers. Must be reached by ALL threads of the block.
__device__ __forceinline__ void col_reduce(const float part[8], float c[8],
                                           float red[8][8], float* bcm,
                                           int wave, int lane, int tid) {
    float r8 = gate_reduce8(part, lane);
    if (lane < 8) {
        int eid = ((lane & 1) << 2) | (lane & 2) | ((lane & 4) >> 2);
        red[wave][eid] = r8;
    }
    __syncthreads();                 // (1) wave partials ready
    if (tid < 8) {
        float s = 0.f;
#pragma unroll
        for (int w = 0; w < 8; w++) s += red[w][tid];
        bcm[tid] = flog2(s);
    }
    __syncthreads();                 // (2) bcm ready
#pragma unroll
    for (int e = 0; e < 8; e++) c[e] = bcm[e];
}

// ---------------- ws layout (bytes) ----------------
// NOTE: rank[] (32*4096 int = 524288 B) reuses OFF_GATES: tmat is dead after
// sinkhorn's final pass; rank_count fully OVERWRITES rank (direct store, no
// atomics), so no pre-zeroing is needed anywhere.
#define OFF_GATES   0u                             // log2-logits, 524288 -> later rank[]
#define OFF_COUNTS  655360u                        // 256
#define OFF_LISTS   655616u                        // 65536
#define OFF_KEYS    753920u                        // 32*4096*8 = 1048576
#define OFF_XBF     1802496u                       // BN*DD*2 = 33554432
#define OFF_EXPT    35356928u                      // EE*DD*DD*2 = 16777216
#define WS_NEEDED   52134144u

// ---- gate logits (blocks 0..511) + counts init (block 512).
// gw fully in registers, 8 tokens/wave; one-token-pair x prefetch pipeline.
// Writes LOG2 of clipped logits (sinkhorn runs in log2 domain; exact
// isomorphism: u = t*log2e, LSE2(u) = LSE(t)*log2e, 2^u_final = e^t_final).
// __launch_bounds__(256,2): VGPR cap 256 so gw preload + prefetch regs fit.
__global__ __launch_bounds__(256, 2) void gate_kernel(const float* __restrict__ x,
                                                      const float* __restrict__ gw,
                                                      float* __restrict__ tmat,
                                                      unsigned short* __restrict__ xbf,
                                                      int* __restrict__ counts) {
    int bid = blockIdx.x;
    int tid = threadIdx.x;
    if (bid >= FRONT_GATE) {
        if (tid < 32) counts[tid] = 0;
        return;
    }
    int wave = tid >> 6, lane = tid & 63;
    float4 g0[4][4], g1[4][4];     // [j][r]: experts 0..3 / 4..7 of row j*256+lane*4+r
#pragma unroll
    for (int j = 0; j < 4; j++)
#pragma unroll
        for (int r = 0; r < 4; r++) {
            const float4* p = (const float4*)(gw + (size_t)(j * 256 + lane * 4 + r) * 8);
            g0[j][r] = p[0];
            g1[j][r] = p[1];
        }
    int tok0 = (bid * 4 + wave) * 8;
    int exp_id = ((lane & 1) << 2) | (lane & 2) | ((lane & 4) >> 2);   // bitrev3

    float4 xa[4], xc[4], na[4], nc[4];
    {
        const float4* xr = (const float4*)(x + (size_t)tok0 * DD);
#pragma unroll
        for (int j = 0; j < 4; j++) xa[j] = xr[j * 64 + lane];
#pragma unroll
        for (int j = 0; j < 4; j++) xc[j] = xr[256 + j * 64 + lane];
    }
#pragma unroll
    for (int tt = 0; tt < 8; tt += 2) {
        int tokA = tok0 + tt, tokB = tokA + 1;
        if (tt < 6) {   // prefetch next pair first: longest-latency ops lead
            const float4* xrn = (const float4*)(x + (size_t)(tokA + 2) * DD);
#pragma unroll
            for (int j = 0; j < 4; j++) na[j] = xrn[j * 64 + lane];
#pragma unroll
            for (int j = 0; j < 4; j++) nc[j] = xrn[256 + j * 64 + lane];
        }
        if (xbf) {   // stores retire without blocking; issue before FMA
#pragma unroll
            for (int j = 0; j < 4; j++) {
                ushort4 o;
                o.x = f2bf(xa[j].x); o.y = f2bf(xa[j].y); o.z = f2bf(xa[j].z); o.w = f2bf(xa[j].w);
                ((ushort4*)(xbf + (size_t)tokA * DD))[j * 64 + lane] = o;
            }
#pragma unroll
            for (int j = 0; j < 4; j++) {
                ushort4 o;
                o.x = f2bf(xc[j].x); o.y = f2bf(xc[j].y); o.z = f2bf(xc[j].z); o.w = f2bf(xc[j].w);
                ((ushort4*)(xbf + (size_t)tokB * DD))[j * 64 + lane] = o;
            }
        }
        float accA[8] = {0.f, 0.f, 0.f, 0.f, 0.f, 0.f, 0.f, 0.f};
        float accB[8] = {0.f, 0.f, 0.f, 0.f, 0.f, 0.f, 0.f, 0.f};
#pragma unroll
        for (int j = 0; j < 4; j++) {
            accA[0] += xa[j].x * g0[j][0].x + xa[j].y * g0[j][1].x + xa[j].z * g0[j][2].x + xa[j].w * g0[j][3].x;
            accA[1] += xa[j].x * g0[j][0].y + xa[j].y * g0[j][1].y + xa[j].z * g0[j][2].y + xa[j].w * g0[j][3].y;
            accA[2] += xa[j].x * g0[j][0].z + xa[j].y * g0[j][1].z + xa[j].z * g0[j][2].z + xa[j].w * g0[j][3].z;
            accA[3] += xa[j].x * g0[j][0].w + xa[j].y * g0[j][1].w + xa[j].z * g0[j][2].w + xa[j].w * g0[j][3].w;
            accA[4] += xa[j].x * g1[j][0].x + xa[j].y * g1[j][1].x + xa[j].z * g1[j][2].x + xa[j].w * g1[j][3].x;
            accA[5] += xa[j].x * g1[j][0].y + xa[j].y * g1[j][1].y + xa[j].z * g1[j][2].y + xa[j].w * g1[j][3].y;
            accA[6] += xa[j].x * g1[j][0].z + xa[j].y * g1[j][1].z + xa[j].z * g1[j][2].z + xa[j].w * g1[j][3].z;
            accA[7] += xa[j].x * g1[j][0].w + xa[j].y * g1[j][1].w + xa[j].z * g1[j][2].w + xa[j].w * g1[j][3].w;
            accB[0] += xc[j].x * g0[j][0].x + xc[j].y * g0[j][1].x + xc[j].z * g0[j][2].x + xc[j].w * g0[j][3].x;
            accB[1] += xc[j].x * g0[j][0].y + xc[j].y * g0[j][1].y + xc[j].z * g0[j][2].y + xc[j].w * g0[j][3].y;
            accB[2] += xc[j].x * g0[j][0].z + xc[j].y * g0[j][1].z + xc[j].z * g0[j][2].z + xc[j].w * g0[j][3].z;
            accB[3] += xc[j].x * g0[j][0].w + xc[j].y * g0[j][1].w + xc[j].z * g0[j][2].w + xc[j].w * g0[j][3].w;
            accB[4] += xc[j].x * g1[j][0].x + xc[j].y * g1[j][1].x + xc[j].z * g1[j][2].x + xc[j].w * g1[j][3].x;
            accB[5] += xc[j].x * g1[j][0].y + xc[j].y * g1[j][1].y + xc[j].z * g1[j][2].y + xc[j].w * g1[j][3].y;
            accB[6] += xc[j].x * g1[j][0].z + xc[j].y * g1[j][1].z + xc[j].z * g1[j][2].z + xc[j].w * g1[j][3].z;
            accB[7] += xc[j].x * g1[j][0].w + xc[j].y * g1[j][1].w + xc[j].z * g1[j][2].w + xc[j].w * g1[j][3].w;
        }
        float vA = gate_reduce8(accA, lane);
        float vB = gate_reduce8(accB, lane);
        if (lane < 8) {
            tmat[(size_t)tokA * EE + exp_id] = flog2(fmaxf(vA, 1e-6f));
            tmat[(size_t)tokB * EE + exp_id] = flog2(fmaxf(vB, 1e-6f));
        }
        if (tt < 6) {
#pragma unroll
            for (int j = 0; j < 4; j++) { xa[j] = na[j]; xc[j] = nc[j]; }
        }
    }
}

// Combined launch, 512 threads/block.
//  blocks 0..3    — sinkhorn, ONE block per batch, log2-domain additive-offset
//                   form: state = c[8] only; re-read t0 from L2 each pass.
//  blocks 4..2051 — expert fp32->bf16 transpose streaming on the idle CUs.
__global__ __launch_bounds__(512) void sinkhorn_conv(const float* __restrict__ tmat,
                                                     unsigned long long* __restrict__ keys,
                                                     const float* __restrict__ E,
                                                     unsigned short* __restrict__ expt) {
    __shared__ float tile[64][65];   // conv path (16.6 KB)
    __shared__ float red[8][8];      // sinkhorn wave partials
    __shared__ float bcm[8];
    int g = blockIdx.x;
    int tid = threadIdx.x;

    if (g >= SKBLK) {
        // ---- experts[e][k][c] fp32 -> expt[e][c][k] bf16, 64x64 tiles ----
        if (!expt) return;
        int cb = g - SKBLK;
        int e = cb >> 8, t = cb & 255;
        int k0 = (t >> 4) * 64, c0 = (t & 15) * 64;
        int r = tid >> 3, c8 = (tid & 7) * 8;
        const float* src = E + ((size_t)e * DD + k0 + r) * DD + c0 + c8;
        float4 v0 = *(const float4*)src;
        float4 v1 = *(const float4*)(src + 4);
        tile[r][c8 + 0] = v0.x; tile[r][c8 + 1] = v0.y; tile[r][c8 + 2] = v0.z; tile[r][c8 + 3] = v0.w;
        tile[r][c8 + 4] = v1.x; tile[r][c8 + 5] = v1.y; tile[r][c8 + 6] = v1.z; tile[r][c8 + 7] = v1.w;
        __syncthreads();
        int cc = tid >> 3, kk8 = (tid & 7) * 8;
        ushort4 o0, o1;
        o0.x = f2bf(tile[kk8 + 0][cc]); o0.y = f2bf(tile[kk8 + 1][cc]);
        o0.z = f2bf(tile[kk8 + 2][cc]); o0.w = f2bf(tile[kk8 + 3][cc]);
        o1.x = f2bf(tile[kk8 + 4][cc]); o1.y = f2bf(tile[kk8 + 5][cc]);
        o1.z = f2bf(tile[kk8 + 6][cc]); o1.w = f2bf(tile[kk8 + 7][cc]);
        unsigned short* dst = expt + ((size_t)e * DD + c0 + cc) * DD + k0 + kk8;
        *(ushort4*)dst = o0;
        *(ushort4*)(dst + 4) = o1;
        return;
    }

    // ---- sinkhorn: batch b = g; rows k*512+tid (k=0..7), 8 iterations ----
    int b = g;
    int wave = tid >> 6, lane = tid & 63;
    const float* tb = tmat + (size_t)b * NN * EE;
    float c[8];

    // pass A: column sums with r=0 -> c_1
    {
        float part[8];
#pragma unroll
        for (int e = 0; e < 8; e++) part[e] = 0.f;
#pragma unroll
        for (int k = 0; k < 8; k++) {
            const float4* p = (const float4*)(tb + (size_t)(k * 512 + tid) * EE);
            float4 v0 = p[0], v1 = p[1];
            part[0] += fexp2(v0.x); part[1] += fexp2(v0.y);
            part[2] += fexp2(v0.z); part[3] += fexp2(v0.w);
            part[4] += fexp2(v1.x); part[5] += fexp2(v1.y);
            part[6] += fexp2(v1.z); part[7] += fexp2(v1.w);
        }
        col_reduce(part, c, red, bcm, wave, lane, tid);
    }

    // 7 fused passes: row update r_j (local) + column partials for c_{j+1}
    for (int it = 0; it < 7; it++) {
        float part[8];
#pragma unroll
        for (int e = 0; e < 8; e++) part[e] = 0.f;
#pragma unroll
        for (int k = 0; k < 8; k++) {
            const float4* p = (const float4*)(tb + (size_t)(k * 512 + tid) * EE);
            float4 v0 = p[0], v1 = p[1];
            float w0 = fexp2(v0.x - c[0]), w1 = fexp2(v0.y - c[1]);
            float w2 = fexp2(v0.z - c[2]), w3 = fexp2(v0.w - c[3]);
            float w4 = fexp2(v1.x - c[4]), w5 = fexp2(v1.y - c[5]);
            float w6 = fexp2(v1.z - c[6]), w7 = fexp2(v1.w - c[7]);
            float s = ((w0 + w1) + (w2 + w3)) + ((w4 + w5) + (w6 + w7));
            float rk = flog2(s);
            part[0] += fexp2(v0.x - rk); part[1] += fexp2(v0.y - rk);
            part[2] += fexp2(v0.z - rk); part[3] += fexp2(v0.w - rk);
            part[4] += fexp2(v1.x - rk); part[5] += fexp2(v1.y - rk);
            part[6] += fexp2(v1.z - rk); part[7] += fexp2(v1.w - rk);
        }
        col_reduce(part, c, red, bcm, wave, lane, tid);
    }

    // final pass: row update r_8, gates = 2^(u0 - c_8 - r_8) = e^t_final -> keys
#pragma unroll
    for (int k = 0; k < 8; k++) {
        int row = k * 512 + tid;
        const float4* p = (const float4*)(tb + (size_t)row * EE);
        float4 v0 = p[0], v1 = p[1];
        float w0 = fexp2(v0.x - c[0]), w1 = fexp2(v0.y - c[1]);
        float w2 = fexp2(v0.z - c[2]), w3 = fexp2(v0.w - c[3]);
        float w4 = fexp2(v1.x - c[4]), w5 = fexp2(v1.y - c[5]);
        float w6 = fexp2(v1.z - c[6]), w7 = fexp2(v1.w - c[7]);
        float s = ((w0 + w1) + (w2 + w3)) + ((w4 + w5) + (w6 + w7));
        float rk = flog2(s);
        unsigned long long rl = (unsigned)(~row);
        keys[(size_t)(b * EE + 0) * NN + row] = ((unsigned long long)__float_as_uint(fexp2(v0.x - c[0] - rk)) << 32) | rl;
        keys[(size_t)(b * EE + 1) * NN + row] = ((unsigned long long)__float_as_uint(fexp2(v0.y - c[1] - rk)) << 32) | rl;
        keys[(size_t)(b * EE + 2) * NN + row] = ((unsigned long long)__float_as_uint(fexp2(v0.z - c[2] - rk)) << 32) | rl;
        keys[(size_t)(b * EE + 3) * NN + row] = ((unsigned long long)__float_as_uint(fexp2(v0.w - c[3] - rk)) << 32) | rl;
        keys[(size_t)(b * EE + 4) * NN + row] = ((unsigned long long)__float_as_uint(fexp2(v1.x - c[4] - rk)) << 32) | rl;
        keys[(size_t)(b * EE + 5) * NN + row] = ((unsigned long long)__float_as_uint(fexp2(v1.y - c[5] - rk)) << 32) | rl;
        keys[(size_t)(b * EE + 6) * NN + row] = ((unsigned long long)__float_as_uint(fexp2(v1.z - c[6] - rk)) << 32) | rl;
        keys[(size_t)(b * EE + 7) * NN + row] = ((unsigned long long)__float_as_uint(fexp2(v1.w - c[7] - rk)) << 32) | rl;
    }
}

// rank v3 (round-11 fix): ballot's popcount was a VALU->SALU round trip
// (~5-7 stall cyc per ballot, serialized) -> VALUBusy 29%. Keep compares
// per-lane in VALU (v_cmp_gt_u64 + v_addc, no SALU readback):
//  - lane l owns token t = bx*64 + l (key in VGPR pair)
//  - wave w owns the 512-key column slice [w*512, w*512+512), streamed
//    wave-uniformly through the SCALAR pipe with an explicit 16-key
//    double-buffer (round-2's prefetch; at 8 waves/SIMD the ~200cy s_load
//    latency hides under 8x64 compare-cycles — round 2 failed only because
//    it ran at 2 waves/SIMD)
//  - 8 per-wave partials per token summed via 2 KB LDS; rank stored
//    DIRECTLY (no atomics, no pre-zeroing).
// grid (64 token-groups, 32 columns) x 512 = 2048 blocks = 8/CU, full waves.
__global__ __launch_bounds__(512) void rank_count_kernel(const unsigned long long* __restrict__ keys,
                                                         int* __restrict__ rank) {
    __shared__ int cnt_s[8][64];   // [wave][token-lane] 2 KB
    int be = blockIdx.y;
    int tid = threadIdx.x;
    int wave = tid >> 6, lane = tid & 63;
    const unsigned long long* kcol = keys + (size_t)be * NN;

    unsigned long long my = kcol[blockIdx.x * 64 + lane];   // per-lane token key
    const unsigned long long* ks = kcol + (size_t)wave * 512;   // wave's slice

    unsigned long long kb[16], kn[16];
#pragma unroll
    for (int i = 0; i < 16; i++) kb[i] = ks[i];

    int c0 = 0, c1 = 0, c2 = 0, c3 = 0;
    for (int j = 0; j < 512; j += 16) {
        if (j + 16 < 512) {   // prefetch next 16 keys (scalar, uniform addr)
#pragma unroll
            for (int i = 0; i < 16; i++) kn[i] = ks[j + 16 + i];
        }
#pragma unroll
        for (int i = 0; i < 16; i += 4) {
            c0 += (int)(kb[i + 0] > my);
            c1 += (int)(kb[i + 1] > my);
            c2 += (int)(kb[i + 2] > my);
            c3 += (int)(kb[i + 3] > my);
        }
        if (j + 16 < 512) {
#pragma unroll
            for (int i = 0; i < 16; i++) kb[i] = kn[i];
        }
    }
    cnt_s[wave][lane] = (c0 + c1) + (c2 + c3);
    __syncthreads();
    if (tid < 64) {
        int s = 0;
#pragma unroll
        for (int w = 0; w < 8; w++) s += cnt_s[w][tid];
        rank[(size_t)be * NN + blockIdx.x * 64 + tid] = s;   // direct store
    }
}

// fused: resolve winners from rank[] + key values -> lists/counts, then zero
// inactive y rows. Winner rule: max (rank*8+e) over selecting experts (numpy
// scatter order), hard-gate (>0.5) checked on the winner only.
__global__ __launch_bounds__(256) void build_zero_kernel(const unsigned long long* __restrict__ keys,
                                                         const int* __restrict__ rank,
                                                         int* __restrict__ counts,
                                                         int* __restrict__ lists,
                                                         float* __restrict__ y) {
    __shared__ int act_s[64];
    int base = blockIdx.x * 64;
    int tid = threadIdx.x;
    if (tid < 64) {
        int i = base + tid;
        int b = i >> 12, tok = i & 4095;
        int wmax = -1;
#pragma unroll
        for (int e = 0; e < EE; e++) {
            int r = rank[(size_t)(b * 8 + e) * NN + tok];
            if (r < MM) {
                int w = r * 8 + e;
                wmax = wmax > w ? wmax : w;
            }
        }
        int active = 0;
        if (wmax >= 0) {
            int ew = wmax & 7;
            unsigned hi = (unsigned)(keys[(size_t)(b * 8 + ew) * NN + tok] >> 32);
            if (__uint_as_float(hi) > 0.5f) {
                int p = atomicAdd(&counts[b * 8 + ew], 1);
                lists[(b * 8 + ew) * MM + p] = tok;
                active = 1;
            }
        }
        act_s[tid] = active;
    }
    __syncthreads();
    float4 z = make_float4(0.f, 0.f, 0.f, 0.f);
    for (int r = 0; r < 64; r++) {
        if (!act_s[r])
            ((float4*)(y + (size_t)(base + r) * DD))[tid] = z;
    }
}

// ---------- bf16 MFMA gathered GEMM: y[b,tok,:] = xbf[b,tok,:] @ expt[e]^T ----------
// 64x128 tile, BK=32; waves 2x2, each wave 2x4 of 16x16x32 MFMA
__global__ __launch_bounds__(256) void expert_gemm_mfma(const unsigned short* __restrict__ xbf,
                                                        const unsigned short* __restrict__ expt,
                                                        const int* __restrict__ counts,
                                                        const int* __restrict__ lists,
                                                        float* __restrict__ y) {
    int be = blockIdx.z;
    int b = be >> 3, e = be & 7;
    int cnt = counts[be];
    int row0 = blockIdx.y * 64;
    if (row0 >= cnt) return;
    int col0 = blockIdx.x * 128;

    __shared__ unsigned short As[64 * 32];    // [row][k] 4 KB
    __shared__ unsigned short Bs[128 * 32];   // [col][k] 8 KB
    __shared__ int toks[64];

    int tid = threadIdx.x;
    int wave = tid >> 6, lane = tid & 63;
    int m16 = lane & 15, quad = lane >> 4;
    int wave_m = wave >> 1, wave_n = wave & 1;

    if (tid < 64) {
        int r = row0 + tid;
        toks[tid] = lists[be * MM + (r < cnt ? r : cnt - 1)];
    }

    int r0 = tid >> 2;
    int ch = tid & 3;

    const unsigned short* xb = xbf + (size_t)b * NN * DD;
    const unsigned short* Eb = expt + (size_t)e * DD * DD;

    floatx4 acc[2][4];
#pragma unroll
    for (int i = 0; i < 2; i++)
#pragma unroll
        for (int j = 0; j < 4; j++) acc[i][j] = (floatx4)0.f;

    for (int k0 = 0; k0 < DD; k0 += 32) {
        __syncthreads();
        {
            const unsigned short* gA  = xb + (size_t)toks[r0] * DD + k0 + ch * 8;
            const unsigned short* gB0 = Eb + (size_t)(col0 + r0) * DD + k0 + ch * 8;
            const unsigned short* gB1 = Eb + (size_t)(col0 + 64 + r0) * DD + k0 + ch * 8;
            __builtin_amdgcn_global_load_lds((gptr_t)gA,  (lptr_t)(As + (size_t)tid * 8), 16, 0, 0);
            __builtin_amdgcn_global_load_lds((gptr_t)gB0, (lptr_t)(Bs + (size_t)tid * 8), 16, 0, 0);
            __builtin_amdgcn_global_load_lds((gptr_t)gB1, (lptr_t)(Bs + 64 * 32 + (size_t)tid * 8), 16, 0, 0);
        }
        __syncthreads();
        bf16x8 af[2], bfr[4];
#pragma unroll
        for (int i = 0; i < 2; i++)
            af[i] = *(const bf16x8*)&As[(wave_m * 32 + i * 16 + m16) * 32 + quad * 8];
#pragma unroll
        for (int j = 0; j < 4; j++)
            bfr[j] = *(const bf16x8*)&Bs[(wave_n * 64 + j * 16 + m16) * 32 + quad * 8];
#pragma unroll
        for (int i = 0; i < 2; i++)
#pragma unroll
            for (int j = 0; j < 4; j++)
                acc[i][j] = __builtin_amdgcn_mfma_f32_16x16x32_bf16(af[i], bfr[j], acc[i][j], 0, 0, 0);
    }

#pragma unroll
    for (int i = 0; i < 2; i++) {
#pragma unroll
        for (int r = 0; r < 4; r++) {
            int lr = wave_m * 32 + i * 16 + quad * 4 + r;
            if (row0 + lr < cnt) {
                int tok = toks[lr];
                float* yr = y + ((size_t)b * NN + tok) * DD + col0 + wave_n * 64 + m16;
#pragma unroll
                for (int j = 0; j < 4; j++) yr[j * 16] = acc[i][j][r];
            }
        }
    }
}

// fallback fp32 GEMM (ws too small for bf16 buffers)
__global__ __launch_bounds__(256) void expert_gemm_kernel(const float* __restrict__ x,
                                                          const float* __restrict__ experts,
                                                          const int* __restrict__ counts,
                                                          const int* __restrict__ lists,
                                                          float* __restrict__ y) {
    int be = blockIdx.z;
    int b = be >> 3, e = be & 7;
    int cnt = counts[be];
    int row0 = blockIdx.y * 64;
    if (row0 >= cnt) return;
    int col0 = blockIdx.x * 64;
    __shared__ float As2[16][68];
    __shared__ float Bs2[16][68];
    __shared__ int toks[64];
    int tid = threadIdx.x;
    if (tid < 64) {
        int r = row0 + tid;
        toks[tid] = (r < cnt) ? lists[be * MM + r] : -1;
    }
    __syncthreads();
    int tx = tid & 15, ty = tid >> 4;
    int ar = tid >> 2;
    int ak = (tid & 3) * 4;
    int bk = tid >> 4;
    int bc4 = (tid & 15) * 4;
    int atok = toks[ar];
    const float* xb = x + (size_t)b * NN * DD;
    const float* Eb = experts + (size_t)e * DD * DD + col0;
    float acc[4][4] = {};
    for (int k0 = 0; k0 < DD; k0 += 16) {
        float4 av;
        if (atok >= 0) av = *(const float4*)(xb + (size_t)atok * DD + k0 + ak);
        else av = make_float4(0.f, 0.f, 0.f, 0.f);
        float4 bv = *(const float4*)(Eb + (size_t)(k0 + bk) * DD + bc4);
        __syncthreads();
        As2[ak + 0][ar] = av.x; As2[ak + 1][ar] = av.y; As2[ak + 2][ar] = av.z; As2[ak + 3][ar] = av.w;
        *(float4*)&Bs2[bk][bc4] = bv;
        __syncthreads();
#pragma unroll
        for (int kk = 0; kk < 16; kk++) {
            float4 a = *(const float4*)&As2[kk][ty * 4];
            float4 bb = *(const float4*)&Bs2[kk][tx * 4];
            acc[0][0] += a.x * bb.x; acc[0][1] += a.x * bb.y; acc[0][2] += a.x * bb.z; acc[0][3] += a.x * bb.w;
            acc[1][0] += a.y * bb.x; acc[1][1] += a.y * bb.y; acc[1][2] += a.y * bb.z; acc[1][3] += a.y * bb.w;
            acc[2][0] += a.z * bb.x; acc[2][1] += a.z * bb.y; acc[2][2] += a.z * bb.z; acc[2][3] += a.z * bb.w;
            acc[3][0] += a.w * bb.x; acc[3][1] += a.w * bb.y; acc[3][2] += a.w * bb.z; acc[3][3] += a.w * bb.w;
        }
    }
#pragma unroll
    for (int i = 0; i < 4; i++) {
        int rl = ty * 4 + i;
        if (row0 + rl < cnt) {
            int tok = toks[rl];
            float4 o = make_float4(acc[i][0], acc[i][1], acc[i][2], acc[i][3]);
            *(float4*)(y + ((size_t)b * NN + tok) * DD + col0 + tx * 4) = o;
        }
    }
}

extern "C" void kernel_launch(void* const* d_in, const int* in_sizes, int n_in,
                              void* d_out, int out_size, void* d_ws, size_t ws_size,
                              hipStream_t stream) {
    const float* x       = (const float*)d_in[0];
    const float* gw      = (const float*)d_in[1];
    const float* experts = (const float*)d_in[2];
    float* y = (float*)d_out;

    char* ws = (char*)d_ws;
    float*    gates    = (float*)(ws + OFF_GATES);
    int*      rank     = (int*)(ws + OFF_GATES);     // overlays gates (dead after sinkhorn)
    int*      counts   = (int*)(ws + OFF_COUNTS);
    int*      lists    = (int*)(ws + OFF_LISTS);
    unsigned long long* keys = (unsigned long long*)(ws + OFF_KEYS);
    bool big = ws_size >= WS_NEEDED;
    unsigned short* xbf  = big ? (unsigned short*)(ws + OFF_XBF)  : nullptr;
    unsigned short* expt = big ? (unsigned short*)(ws + OFF_EXPT) : nullptr;

    gate_kernel<<<FRONT_GATE + 1, 256, 0, stream>>>(x, gw, gates, xbf, counts);
    sinkhorn_conv<<<SKBLK + FRONT_CONV, 512, 0, stream>>>(gates, keys, experts, expt);
    rank_count_kernel<<<dim3(NN / 64, 32), 512, 0, stream>>>(keys, rank);
    build_zero_kernel<<<256, 256, 0, stream>>>(keys, rank, counts, lists, y);
    if (big)
        expert_gemm_mfma<<<dim3(8, 8, BB * EE), 256, 0, stream>>>(xbf, expt, counts, lists, y);
    else
        expert_gemm_kernel<<<dim3(16, 8, BB * EE), 256, 0, stream>>>(x, experts, counts, lists, y);
}

// Round 13
// 253.710 us; speedup vs baseline: 1.3229x; 1.3229x over previous
//
#include <hip/hip_runtime.h>
#include <hip/hip_bf16.h>
#include <stdint.h>

#define BB 4
#define NN 4096
#define DD 1024
#define EE 8
#define MM 512
#define BN (BB*NN)   // 16384

#define FRONT_GATE 512
#define FRONT_CONV 2048
#define SKBLK 4      // sinkhorn blocks (1 per batch, 512 threads, LDS-local)

typedef __bf16 bf16x8 __attribute__((ext_vector_type(8)));
typedef float  floatx4 __attribute__((ext_vector_type(4)));

typedef const __attribute__((address_space(1))) void* gptr_t;
typedef __attribute__((address_space(3))) void* lptr_t;

__device__ __forceinline__ unsigned short f2bf(float f) {
    union { float f; unsigned u; } v; v.f = f;
    unsigned r = v.u + 0x7fffu + ((v.u >> 16) & 1u);   // round-to-nearest-even
    return (unsigned short)(r >> 16);
}

// raw HW transcendentals: v_exp_f32 = 2^x, v_log_f32 = log2(x), 1 instr each.
// (round-9 fix: precise expf/logf lower to ~10-op OCML sequences; the sinkhorn
// tail on 4 CUs was libm-expansion-bound at ~60 us)
__device__ __forceinline__ float fexp2(float x) { return __builtin_amdgcn_exp2f(x); }
__device__ __forceinline__ float flog2(float x) { return __builtin_amdgcn_logf(x); }

// packed tree reduction: acc[8] per lane summed over 64 lanes.
// returns: lane l (any l) holds full sum of expert bitrev3(l&7) = ((l&1)<<2)|(l&2)|((l&4)>>2)
__device__ __forceinline__ float gate_reduce8(const float acc[8], int lane) {
    float k1[4];
#pragma unroll
    for (int e = 0; e < 4; e++) {
        float a = acc[e]     + __shfl_xor(acc[e],     1, 64);
        float b = acc[e + 4] + __shfl_xor(acc[e + 4], 1, 64);
        k1[e] = (lane & 1) ? b : a;
    }
    float k2[2];
#pragma unroll
    for (int e = 0; e < 2; e++) {
        float a = k1[e]     + __shfl_xor(k1[e],     2, 64);
        float b = k1[e + 2] + __shfl_xor(k1[e + 2], 2, 64);
        k2[e] = (lane & 2) ? b : a;
    }
    float a = k2[0] + __shfl_xor(k2[0], 4, 64);
    float b = k2[1] + __shfl_xor(k2[1], 4, 64);
    float v = (lane & 4) ? b : a;
    v += __shfl_xor(v, 8, 64);
    v += __shfl_xor(v, 16, 64);
    v += __shfl_xor(v, 32, 64);
    return v;
}

// block-level column reduction: part[8] per thread -> c[8] (log2 of column sums).
// Uses red/bcm LDS; 2 barriers. Must be reached by ALL threads of the block.
__device__ __forceinline__ void col_reduce(const float part[8], float c[8],
                                           float red[8][8], float* bcm,
                                           int wave, int lane, int tid) {
    float r8 = gate_reduce8(part, lane);
    if (lane < 8) {
        int eid = ((lane & 1) << 2) | (lane & 2) | ((lane & 4) >> 2);
        red[wave][eid] = r8;
    }
    __syncthreads();                 // (1) wave partials ready
    if (tid < 8) {
        float s = 0.f;
#pragma unroll
        for (int w = 0; w < 8; w++) s += red[w][tid];
        bcm[tid] = flog2(s);
    }
    __syncthreads();                 // (2) bcm ready
#pragma unroll
    for (int e = 0; e < 8; e++) c[e] = bcm[e];
}

// ---------------- ws layout (bytes) ----------------
// NOTE: rank[] (32*4096 int = 524288 B) reuses OFF_GATES: tmat is dead after
// sinkhorn's final pass; rank_count fully OVERWRITES rank (direct store, no
// atomics), so no pre-zeroing is needed anywhere.
#define OFF_GATES   0u                             // log2-logits, 524288 -> later rank[]
#define OFF_COUNTS  655360u                        // 256
#define OFF_LISTS   655616u                        // 65536
#define OFF_KEYS    753920u                        // 32*4096*8 = 1048576
#define OFF_XBF     1802496u                       // BN*DD*2 = 33554432
#define OFF_EXPT    35356928u                      // EE*DD*DD*2 = 16777216
#define WS_NEEDED   52134144u

// ---- gate logits (blocks 0..511) + counts init (block 512).
// gw fully in registers, 8 tokens/wave; one-token-pair x prefetch pipeline.
// Writes LOG2 of clipped logits (sinkhorn runs in log2 domain; exact
// isomorphism: u = t*log2e, LSE2(u) = LSE(t)*log2e, 2^u_final = e^t_final).
// __launch_bounds__(256,2): VGPR cap 256 so gw preload + prefetch regs fit.
__global__ __launch_bounds__(256, 2) void gate_kernel(const float* __restrict__ x,
                                                      const float* __restrict__ gw,
                                                      float* __restrict__ tmat,
                                                      unsigned short* __restrict__ xbf,
                                                      int* __restrict__ counts) {
    int bid = blockIdx.x;
    int tid = threadIdx.x;
    if (bid >= FRONT_GATE) {
        if (tid < 32) counts[tid] = 0;
        return;
    }
    int wave = tid >> 6, lane = tid & 63;
    float4 g0[4][4], g1[4][4];     // [j][r]: experts 0..3 / 4..7 of row j*256+lane*4+r
#pragma unroll
    for (int j = 0; j < 4; j++)
#pragma unroll
        for (int r = 0; r < 4; r++) {
            const float4* p = (const float4*)(gw + (size_t)(j * 256 + lane * 4 + r) * 8);
            g0[j][r] = p[0];
            g1[j][r] = p[1];
        }
    int tok0 = (bid * 4 + wave) * 8;
    int exp_id = ((lane & 1) << 2) | (lane & 2) | ((lane & 4) >> 2);   // bitrev3

    float4 xa[4], xc[4], na[4], nc[4];
    {
        const float4* xr = (const float4*)(x + (size_t)tok0 * DD);
#pragma unroll
        for (int j = 0; j < 4; j++) xa[j] = xr[j * 64 + lane];
#pragma unroll
        for (int j = 0; j < 4; j++) xc[j] = xr[256 + j * 64 + lane];
    }
#pragma unroll
    for (int tt = 0; tt < 8; tt += 2) {
        int tokA = tok0 + tt, tokB = tokA + 1;
        if (tt < 6) {   // prefetch next pair first: longest-latency ops lead
            const float4* xrn = (const float4*)(x + (size_t)(tokA + 2) * DD);
#pragma unroll
            for (int j = 0; j < 4; j++) na[j] = xrn[j * 64 + lane];
#pragma unroll
            for (int j = 0; j < 4; j++) nc[j] = xrn[256 + j * 64 + lane];
        }
        if (xbf) {   // stores retire without blocking; issue before FMA
#pragma unroll
            for (int j = 0; j < 4; j++) {
                ushort4 o;
                o.x = f2bf(xa[j].x); o.y = f2bf(xa[j].y); o.z = f2bf(xa[j].z); o.w = f2bf(xa[j].w);
                ((ushort4*)(xbf + (size_t)tokA * DD))[j * 64 + lane] = o;
            }
#pragma unroll
            for (int j = 0; j < 4; j++) {
                ushort4 o;
                o.x = f2bf(xc[j].x); o.y = f2bf(xc[j].y); o.z = f2bf(xc[j].z); o.w = f2bf(xc[j].w);
                ((ushort4*)(xbf + (size_t)tokB * DD))[j * 64 + lane] = o;
            }
        }
        float accA[8] = {0.f, 0.f, 0.f, 0.f, 0.f, 0.f, 0.f, 0.f};
        float accB[8] = {0.f, 0.f, 0.f, 0.f, 0.f, 0.f, 0.f, 0.f};
#pragma unroll
        for (int j = 0; j < 4; j++) {
            accA[0] += xa[j].x * g0[j][0].x + xa[j].y * g0[j][1].x + xa[j].z * g0[j][2].x + xa[j].w * g0[j][3].x;
            accA[1] += xa[j].x * g0[j][0].y + xa[j].y * g0[j][1].y + xa[j].z * g0[j][2].y + xa[j].w * g0[j][3].y;
            accA[2] += xa[j].x * g0[j][0].z + xa[j].y * g0[j][1].z + xa[j].z * g0[j][2].z + xa[j].w * g0[j][3].z;
            accA[3] += xa[j].x * g0[j][0].w + xa[j].y * g0[j][1].w + xa[j].z * g0[j][2].w + xa[j].w * g0[j][3].w;
            accA[4] += xa[j].x * g1[j][0].x + xa[j].y * g1[j][1].x + xa[j].z * g1[j][2].x + xa[j].w * g1[j][3].x;
            accA[5] += xa[j].x * g1[j][0].y + xa[j].y * g1[j][1].y + xa[j].z * g1[j][2].y + xa[j].w * g1[j][3].y;
            accA[6] += xa[j].x * g1[j][0].z + xa[j].y * g1[j][1].z + xa[j].z * g1[j][2].z + xa[j].w * g1[j][3].z;
            accA[7] += xa[j].x * g1[j][0].w + xa[j].y * g1[j][1].w + xa[j].z * g1[j][2].w + xa[j].w * g1[j][3].w;
            accB[0] += xc[j].x * g0[j][0].x + xc[j].y * g0[j][1].x + xc[j].z * g0[j][2].x + xc[j].w * g0[j][3].x;
            accB[1] += xc[j].x * g0[j][0].y + xc[j].y * g0[j][1].y + xc[j].z * g0[j][2].y + xc[j].w * g0[j][3].y;
            accB[2] += xc[j].x * g0[j][0].z + xc[j].y * g0[j][1].z + xc[j].z * g0[j][2].z + xc[j].w * g0[j][3].z;
            accB[3] += xc[j].x * g0[j][0].w + xc[j].y * g0[j][1].w + xc[j].z * g0[j][2].w + xc[j].w * g0[j][3].w;
            accB[4] += xc[j].x * g1[j][0].x + xc[j].y * g1[j][1].x + xc[j].z * g1[j][2].x + xc[j].w * g1[j][3].x;
            accB[5] += xc[j].x * g1[j][0].y + xc[j].y * g1[j][1].y + xc[j].z * g1[j][2].y + xc[j].w * g1[j][3].y;
            accB[6] += xc[j].x * g1[j][0].z + xc[j].y * g1[j][1].z + xc[j].z * g1[j][2].z + xc[j].w * g1[j][3].z;
            accB[7] += xc[j].x * g1[j][0].w + xc[j].y * g1[j][1].w + xc[j].z * g1[j][2].w + xc[j].w * g1[j][3].w;
        }
        float vA = gate_reduce8(accA, lane);
        float vB = gate_reduce8(accB, lane);
        if (lane < 8) {
            tmat[(size_t)tokA * EE + exp_id] = flog2(fmaxf(vA, 1e-6f));
            tmat[(size_t)tokB * EE + exp_id] = flog2(fmaxf(vB, 1e-6f));
        }
        if (tt < 6) {
#pragma unroll
            for (int j = 0; j < 4; j++) { xa[j] = na[j]; xc[j] = nc[j]; }
        }
    }
}

// Combined launch, 512 threads/block.
//  blocks 0..3    — sinkhorn, ONE block per batch, log2-domain additive-offset
//                   form: state = c[8] only; re-read t0 from L2 each pass.
//  blocks 4..2051 — expert fp32->bf16 transpose streaming on the idle CUs.
__global__ __launch_bounds__(512) void sinkhorn_conv(const float* __restrict__ tmat,
                                                     unsigned long long* __restrict__ keys,
                                                     const float* __restrict__ E,
                                                     unsigned short* __restrict__ expt) {
    __shared__ float tile[64][65];   // conv path (16.6 KB)
    __shared__ float red[8][8];      // sinkhorn wave partials
    __shared__ float bcm[8];
    int g = blockIdx.x;
    int tid = threadIdx.x;

    if (g >= SKBLK) {
        // ---- experts[e][k][c] fp32 -> expt[e][c][k] bf16, 64x64 tiles ----
        if (!expt) return;
        int cb = g - SKBLK;
        int e = cb >> 8, t = cb & 255;
        int k0 = (t >> 4) * 64, c0 = (t & 15) * 64;
        int r = tid >> 3, c8 = (tid & 7) * 8;
        const float* src = E + ((size_t)e * DD + k0 + r) * DD + c0 + c8;
        float4 v0 = *(const float4*)src;
        float4 v1 = *(const float4*)(src + 4);
        tile[r][c8 + 0] = v0.x; tile[r][c8 + 1] = v0.y; tile[r][c8 + 2] = v0.z; tile[r][c8 + 3] = v0.w;
        tile[r][c8 + 4] = v1.x; tile[r][c8 + 5] = v1.y; tile[r][c8 + 6] = v1.z; tile[r][c8 + 7] = v1.w;
        __syncthreads();
        int cc = tid >> 3, kk8 = (tid & 7) * 8;
        ushort4 o0, o1;
        o0.x = f2bf(tile[kk8 + 0][cc]); o0.y = f2bf(tile[kk8 + 1][cc]);
        o0.z = f2bf(tile[kk8 + 2][cc]); o0.w = f2bf(tile[kk8 + 3][cc]);
        o1.x = f2bf(tile[kk8 + 4][cc]); o1.y = f2bf(tile[kk8 + 5][cc]);
        o1.z = f2bf(tile[kk8 + 6][cc]); o1.w = f2bf(tile[kk8 + 7][cc]);
        unsigned short* dst = expt + ((size_t)e * DD + c0 + cc) * DD + k0 + kk8;
        *(ushort4*)dst = o0;
        *(ushort4*)(dst + 4) = o1;
        return;
    }

    // ---- sinkhorn: batch b = g; rows k*512+tid (k=0..7), 8 iterations ----
    int b = g;
    int wave = tid >> 6, lane = tid & 63;
    const float* tb = tmat + (size_t)b * NN * EE;
    float c[8];

    // pass A: column sums with r=0 -> c_1
    {
        float part[8];
#pragma unroll
        for (int e = 0; e < 8; e++) part[e] = 0.f;
#pragma unroll
        for (int k = 0; k < 8; k++) {
            const float4* p = (const float4*)(tb + (size_t)(k * 512 + tid) * EE);
            float4 v0 = p[0], v1 = p[1];
            part[0] += fexp2(v0.x); part[1] += fexp2(v0.y);
            part[2] += fexp2(v0.z); part[3] += fexp2(v0.w);
            part[4] += fexp2(v1.x); part[5] += fexp2(v1.y);
            part[6] += fexp2(v1.z); part[7] += fexp2(v1.w);
        }
        col_reduce(part, c, red, bcm, wave, lane, tid);
    }

    // 7 fused passes: row update r_j (local) + column partials for c_{j+1}
    for (int it = 0; it < 7; it++) {
        float part[8];
#pragma unroll
        for (int e = 0; e < 8; e++) part[e] = 0.f;
#pragma unroll
        for (int k = 0; k < 8; k++) {
            const float4* p = (const float4*)(tb + (size_t)(k * 512 + tid) * EE);
            float4 v0 = p[0], v1 = p[1];
            float w0 = fexp2(v0.x - c[0]), w1 = fexp2(v0.y - c[1]);
            float w2 = fexp2(v0.z - c[2]), w3 = fexp2(v0.w - c[3]);
            float w4 = fexp2(v1.x - c[4]), w5 = fexp2(v1.y - c[5]);
            float w6 = fexp2(v1.z - c[6]), w7 = fexp2(v1.w - c[7]);
            float s = ((w0 + w1) + (w2 + w3)) + ((w4 + w5) + (w6 + w7));
            float rk = flog2(s);
            part[0] += fexp2(v0.x - rk); part[1] += fexp2(v0.y - rk);
            part[2] += fexp2(v0.z - rk); part[3] += fexp2(v0.w - rk);
            part[4] += fexp2(v1.x - rk); part[5] += fexp2(v1.y - rk);
            part[6] += fexp2(v1.z - rk); part[7] += fexp2(v1.w - rk);
        }
        col_reduce(part, c, red, bcm, wave, lane, tid);
    }

    // final pass: row update r_8, gates = 2^(u0 - c_8 - r_8) = e^t_final -> keys
#pragma unroll
    for (int k = 0; k < 8; k++) {
        int row = k * 512 + tid;
        const float4* p = (const float4*)(tb + (size_t)row * EE);
        float4 v0 = p[0], v1 = p[1];
        float w0 = fexp2(v0.x - c[0]), w1 = fexp2(v0.y - c[1]);
        float w2 = fexp2(v0.z - c[2]), w3 = fexp2(v0.w - c[3]);
        float w4 = fexp2(v1.x - c[4]), w5 = fexp2(v1.y - c[5]);
        float w6 = fexp2(v1.z - c[6]), w7 = fexp2(v1.w - c[7]);
        float s = ((w0 + w1) + (w2 + w3)) + ((w4 + w5) + (w6 + w7));
        float rk = flog2(s);
        unsigned long long rl = (unsigned)(~row);
        keys[(size_t)(b * EE + 0) * NN + row] = ((unsigned long long)__float_as_uint(fexp2(v0.x - c[0] - rk)) << 32) | rl;
        keys[(size_t)(b * EE + 1) * NN + row] = ((unsigned long long)__float_as_uint(fexp2(v0.y - c[1] - rk)) << 32) | rl;
        keys[(size_t)(b * EE + 2) * NN + row] = ((unsigned long long)__float_as_uint(fexp2(v0.z - c[2] - rk)) << 32) | rl;
        keys[(size_t)(b * EE + 3) * NN + row] = ((unsigned long long)__float_as_uint(fexp2(v0.w - c[3] - rk)) << 32) | rl;
        keys[(size_t)(b * EE + 4) * NN + row] = ((unsigned long long)__float_as_uint(fexp2(v1.x - c[4] - rk)) << 32) | rl;
        keys[(size_t)(b * EE + 5) * NN + row] = ((unsigned long long)__float_as_uint(fexp2(v1.y - c[5] - rk)) << 32) | rl;
        keys[(size_t)(b * EE + 6) * NN + row] = ((unsigned long long)__float_as_uint(fexp2(v1.z - c[6] - rk)) << 32) | rl;
        keys[(size_t)(b * EE + 7) * NN + row] = ((unsigned long long)__float_as_uint(fexp2(v1.w - c[7] - rk)) << 32) | rl;
    }
}

// rank v4 (round-12 fix): v3's wave-slice pointer ks = kcol + wave*512 used
// wave = tid>>6, which the compiler could NOT prove wave-uniform -> the key
// stream compiled to per-lane flat loads of identical addresses (SGPR=32,
// 64x issue amplification, vmcnt-serialized, 128 us). Fix: wave id through
// __builtin_amdgcn_readfirstlane -> SGPR; slice address arithmetic stays
// scalar; the unrolled 16-key double-buffer lowers to s_load_dwordx16
// (round 2 proved the pattern: SGPR=96). Compares stay per-lane in VALU
// (v_cmp_gt_u64 + v_addc, 4 independent accumulators, no SALU readback).
// Per-token partials from 8 waves sum via 2 KB LDS; rank stored DIRECTLY.
// grid (64 token-groups, 32 columns) x 512 = 2048 blocks = 8/CU, full waves.
__global__ __launch_bounds__(512) void rank_count_kernel(const unsigned long long* __restrict__ keys,
                                                         int* __restrict__ rank) {
    __shared__ int cnt_s[8][64];   // [wave][token-lane] 2 KB
    int be = blockIdx.y;
    int tid = threadIdx.x;
    int lane = tid & 63;
    int wave = __builtin_amdgcn_readfirstlane(tid >> 6);   // force SGPR wave id
    const unsigned long long* kcol = keys + (size_t)be * NN;

    unsigned long long my = kcol[blockIdx.x * 64 + lane];       // per-lane token key
    const unsigned long long* ks = kcol + (size_t)wave * 512;   // SCALAR slice base

    unsigned long long kb[16], kn[16];
#pragma unroll
    for (int i = 0; i < 16; i++) kb[i] = ks[i];

    int c0 = 0, c1 = 0, c2 = 0, c3 = 0;
    for (int j = 0; j < 512; j += 16) {
        if (j + 16 < 512) {   // prefetch next 16 keys (s_load, uniform addr)
#pragma unroll
            for (int i = 0; i < 16; i++) kn[i] = ks[j + 16 + i];
        }
#pragma unroll
        for (int i = 0; i < 16; i += 4) {
            c0 += (int)(kb[i + 0] > my);
            c1 += (int)(kb[i + 1] > my);
            c2 += (int)(kb[i + 2] > my);
            c3 += (int)(kb[i + 3] > my);
        }
        if (j + 16 < 512) {
#pragma unroll
            for (int i = 0; i < 16; i++) kb[i] = kn[i];
        }
    }
    cnt_s[wave][lane] = (c0 + c1) + (c2 + c3);
    __syncthreads();
    if (tid < 64) {
        int s = 0;
#pragma unroll
        for (int w = 0; w < 8; w++) s += cnt_s[w][tid];
        rank[(size_t)be * NN + blockIdx.x * 64 + tid] = s;   // direct store
    }
}

// fused: resolve winners from rank[] + key values -> lists/counts, then zero
// inactive y rows. Winner rule: max (rank*8+e) over selecting experts (numpy
// scatter order), hard-gate (>0.5) checked on the winner only.
__global__ __launch_bounds__(256) void build_zero_kernel(const unsigned long long* __restrict__ keys,
                                                         const int* __restrict__ rank,
                                                         int* __restrict__ counts,
                                                         int* __restrict__ lists,
                                                         float* __restrict__ y) {
    __shared__ int act_s[64];
    int base = blockIdx.x * 64;
    int tid = threadIdx.x;
    if (tid < 64) {
        int i = base + tid;
        int b = i >> 12, tok = i & 4095;
        int wmax = -1;
#pragma unroll
        for (int e = 0; e < EE; e++) {
            int r = rank[(size_t)(b * 8 + e) * NN + tok];
            if (r < MM) {
                int w = r * 8 + e;
                wmax = wmax > w ? wmax : w;
            }
        }
        int active = 0;
        if (wmax >= 0) {
            int ew = wmax & 7;
            unsigned hi = (unsigned)(keys[(size_t)(b * 8 + ew) * NN + tok] >> 32);
            if (__uint_as_float(hi) > 0.5f) {
                int p = atomicAdd(&counts[b * 8 + ew], 1);
                lists[(b * 8 + ew) * MM + p] = tok;
                active = 1;
            }
        }
        act_s[tid] = active;
    }
    __syncthreads();
    float4 z = make_float4(0.f, 0.f, 0.f, 0.f);
    for (int r = 0; r < 64; r++) {
        if (!act_s[r])
            ((float4*)(y + (size_t)(base + r) * DD))[tid] = z;
    }
}

// ---------- bf16 MFMA gathered GEMM: y[b,tok,:] = xbf[b,tok,:] @ expt[e]^T ----------
// 64x128 tile, BK=32; waves 2x2, each wave 2x4 of 16x16x32 MFMA
__global__ __launch_bounds__(256) void expert_gemm_mfma(const unsigned short* __restrict__ xbf,
                                                        const unsigned short* __restrict__ expt,
                                                        const int* __restrict__ counts,
                                                        const int* __restrict__ lists,
                                                        float* __restrict__ y) {
    int be = blockIdx.z;
    int b = be >> 3, e = be & 7;
    int cnt = counts[be];
    int row0 = blockIdx.y * 64;
    if (row0 >= cnt) return;
    int col0 = blockIdx.x * 128;

    __shared__ unsigned short As[64 * 32];    // [row][k] 4 KB
    __shared__ unsigned short Bs[128 * 32];   // [col][k] 8 KB
    __shared__ int toks[64];

    int tid = threadIdx.x;
    int wave = tid >> 6, lane = tid & 63;
    int m16 = lane & 15, quad = lane >> 4;
    int wave_m = wave >> 1, wave_n = wave & 1;

    if (tid < 64) {
        int r = row0 + tid;
        toks[tid] = lists[be * MM + (r < cnt ? r : cnt - 1)];
    }

    int r0 = tid >> 2;
    int ch = tid & 3;

    const unsigned short* xb = xbf + (size_t)b * NN * DD;
    const unsigned short* Eb = expt + (size_t)e * DD * DD;

    floatx4 acc[2][4];
#pragma unroll
    for (int i = 0; i < 2; i++)
#pragma unroll
        for (int j = 0; j < 4; j++) acc[i][j] = (floatx4)0.f;

    for (int k0 = 0; k0 < DD; k0 += 32) {
        __syncthreads();
        {
            const unsigned short* gA  = xb + (size_t)toks[r0] * DD + k0 + ch * 8;
            const unsigned short* gB0 = Eb + (size_t)(col0 + r0) * DD + k0 + ch * 8;
            const unsigned short* gB1 = Eb + (size_t)(col0 + 64 + r0) * DD + k0 + ch * 8;
            __builtin_amdgcn_global_load_lds((gptr_t)gA,  (lptr_t)(As + (size_t)tid * 8), 16, 0, 0);
            __builtin_amdgcn_global_load_lds((gptr_t)gB0, (lptr_t)(Bs + (size_t)tid * 8), 16, 0, 0);
            __builtin_amdgcn_global_load_lds((gptr_t)gB1, (lptr_t)(Bs + 64 * 32 + (size_t)tid * 8), 16, 0, 0);
        }
        __syncthreads();
        bf16x8 af[2], bfr[4];
#pragma unroll
        for (int i = 0; i < 2; i++)
            af[i] = *(const bf16x8*)&As[(wave_m * 32 + i * 16 + m16) * 32 + quad * 8];
#pragma unroll
        for (int j = 0; j < 4; j++)
            bfr[j] = *(const bf16x8*)&Bs[(wave_n * 64 + j * 16 + m16) * 32 + quad * 8];
#pragma unroll
        for (int i = 0; i < 2; i++)
#pragma unroll
            for (int j = 0; j < 4; j++)
                acc[i][j] = __builtin_amdgcn_mfma_f32_16x16x32_bf16(af[i], bfr[j], acc[i][j], 0, 0, 0);
    }

#pragma unroll
    for (int i = 0; i < 2; i++) {
#pragma unroll
        for (int r = 0; r < 4; r++) {
            int lr = wave_m * 32 + i * 16 + quad * 4 + r;
            if (row0 + lr < cnt) {
                int tok = toks[lr];
                float* yr = y + ((size_t)b * NN + tok) * DD + col0 + wave_n * 64 + m16;
#pragma unroll
                for (int j = 0; j < 4; j++) yr[j * 16] = acc[i][j][r];
            }
        }
    }
}

// fallback fp32 GEMM (ws too small for bf16 buffers)
__global__ __launch_bounds__(256) void expert_gemm_kernel(const float* __restrict__ x,
                                                          const float* __restrict__ experts,
                                                          const int* __restrict__ counts,
                                                          const int* __restrict__ lists,
                                                          float* __restrict__ y) {
    int be = blockIdx.z;
    int b = be >> 3, e = be & 7;
    int cnt = counts[be];
    int row0 = blockIdx.y * 64;
    if (row0 >= cnt) return;
    int col0 = blockIdx.x * 64;
    __shared__ float As2[16][68];
    __shared__ float Bs2[16][68];
    __shared__ int toks[64];
    int tid = threadIdx.x;
    if (tid < 64) {
        int r = row0 + tid;
        toks[tid] = (r < cnt) ? lists[be * MM + r] : -1;
    }
    __syncthreads();
    int tx = tid & 15, ty = tid >> 4;
    int ar = tid >> 2;
    int ak = (tid & 3) * 4;
    int bk = tid >> 4;
    int bc4 = (tid & 15) * 4;
    int atok = toks[ar];
    const float* xb = x + (size_t)b * NN * DD;
    const float* Eb = experts + (size_t)e * DD * DD + col0;
    float acc[4][4] = {};
    for (int k0 = 0; k0 < DD; k0 += 16) {
        float4 av;
        if (atok >= 0) av = *(const float4*)(xb + (size_t)atok * DD + k0 + ak);
        else av = make_float4(0.f, 0.f, 0.f, 0.f);
        float4 bv = *(const float4*)(Eb + (size_t)(k0 + bk) * DD + bc4);
        __syncthreads();
        As2[ak + 0][ar] = av.x; As2[ak + 1][ar] = av.y; As2[ak + 2][ar] = av.z; As2[ak + 3][ar] = av.w;
        *(float4*)&Bs2[bk][bc4] = bv;
        __syncthreads();
#pragma unroll
        for (int kk = 0; kk < 16; kk++) {
            float4 a = *(const float4*)&As2[kk][ty * 4];
            float4 bb = *(const float4*)&Bs2[kk][tx * 4];
            acc[0][0] += a.x * bb.x; acc[0][1] += a.x * bb.y; acc[0][2] += a.x * bb.z; acc[0][3] += a.x * bb.w;
            acc[1][0] += a.y * bb.x; acc[1][1] += a.y * bb.y; acc[1][2] += a.y * bb.z; acc[1][3] += a.y * bb.w;
            acc[2][0] += a.z * bb.x; acc[2][1] += a.z * bb.y; acc[2][2] += a.z * bb.z; acc[2][3] += a.z * bb.w;
            acc[3][0] += a.w * bb.x; acc[3][1] += a.w * bb.y; acc[3][2] += a.w * bb.z; acc[3][3] += a.w * bb.w;
        }
    }
#pragma unroll
    for (int i = 0; i < 4; i++) {
        int rl = ty * 4 + i;
        if (row0 + rl < cnt) {
            int tok = toks[rl];
            float4 o = make_float4(acc[i][0], acc[i][1], acc[i][2], acc[i][3]);
            *(float4*)(y + ((size_t)b * NN + tok) * DD + col0 + tx * 4) = o;
        }
    }
}

extern "C" void kernel_launch(void* const* d_in, const int* in_sizes, int n_in,
                              void* d_out, int out_size, void* d_ws, size_t ws_size,
                              hipStream_t stream) {
    const float* x       = (const float*)d_in[0];
    const float* gw      = (const float*)d_in[1];
    const float* experts = (const float*)d_in[2];
    float* y = (float*)d_out;

    char* ws = (char*)d_ws;
    float*    gates    = (float*)(ws + OFF_GATES);
    int*      rank     = (int*)(ws + OFF_GATES);     // overlays gates (dead after sinkhorn)
    int*      counts   = (int*)(ws + OFF_COUNTS);
    int*      lists    = (int*)(ws + OFF_LISTS);
    unsigned long long* keys = (unsigned long long*)(ws + OFF_KEYS);
    bool big = ws_size >= WS_NEEDED;
    unsigned short* xbf  = big ? (unsigned short*)(ws + OFF_XBF)  : nullptr;
    unsigned short* expt = big ? (unsigned short*)(ws + OFF_EXPT) : nullptr;

    gate_kernel<<<FRONT_GATE + 1, 256, 0, stream>>>(x, gw, gates, xbf, counts);
    sinkhorn_conv<<<SKBLK + FRONT_CONV, 512, 0, stream>>>(gates, keys, experts, expt);
    rank_count_kernel<<<dim3(NN / 64, 32), 512, 0, stream>>>(keys, rank);
    build_zero_kernel<<<256, 256, 0, stream>>>(keys, rank, counts, lists, y);
    if (big)
        expert_gemm_mfma<<<dim3(8, 8, BB * EE), 256, 0, stream>>>(xbf, expt, counts, lists, y);
    else
        expert_gemm_kernel<<<dim3(16, 8, BB * EE), 256, 0, stream>>>(x, experts, counts, lists, y);
}